// Round 9
// baseline (433.368 us; speedup 1.0000x reference)
//
#include <hip/hip_runtime.h>

// Stream_PreNet split pipeline: conv1 (1x7, 8->96) and conv2 (7x1, 96->96) as
// TWO mono-phase streaming kernels; intermediate out1 (NHWC bf16, 201MB) in d_ws.
// Rationale (R2/R7/R8 counters): every fused multi-phase structure trips
// compiler spill/remat (VGPR_Count 40-64, +130MB scratch WRITE) and sits at
// MfmaUtil 27% / nothing saturated. Mono-phase kernels: no LDS, no syncthreads,
// phase-local register sets, pure stream.
// Fallback: if ws_size too small for out1, run the proven fused R6 kernel.
// d_ws: w1t(12,288B) + w2t(129,024B) + bias2e(384B) [+ pad to 141,824] + out1.

#define B_   8
#define H_   512
#define W_   256
#define CIN  8
#define COUT 96
#define TW   16           // pixels (w) per block
#define TH1  8            // conv1 rows per block
#define TH2  16           // conv2 output rows per block
#define RB   (TH2 + 6)    // 22 input rows for conv2 tile
// fused fallback geometry
#define TH   8
#define ROWS (TH + 6)
#define XC   (TW + 6)
#define NTHREADS 384

typedef __bf16 bf16x8 __attribute__((ext_vector_type(8)));
typedef float  f32x4  __attribute__((ext_vector_type(4)));
typedef int    i32x4  __attribute__((ext_vector_type(4)));

__device__ __forceinline__ unsigned short f2bf(float f) {
  unsigned u = __builtin_bit_cast(unsigned, f);
  u += 0x7FFFu + ((u >> 16) & 1u);   // RNE
  return (unsigned short)(u >> 16);
}

__device__ __forceinline__ bf16x8 ld16s(const unsigned short* p) {
  i32x4 t = *(const i32x4*)p;        // 16B load -> ds_read_b128 / global dwordx4
  return __builtin_bit_cast(bf16x8, t);
}

__device__ __forceinline__ f32x4 mfma16(bf16x8 a, bf16x8 b, f32x4 c) {
  return __builtin_amdgcn_mfma_f32_16x16x32_bf16(a, b, c, 0, 0, 0);
}

// jnp.pad mode='symmetric': -1->0, -2->1 ; N->N-1, N+1->N-2
__device__ __forceinline__ int symH(int i) { return i < 0 ? -1 - i : (i >= H_ ? 2 * H_ - 1 - i : i); }
__device__ __forceinline__ int symW(int i) { return i < 0 ? -1 - i : (i >= W_ ? 2 * W_ - 1 - i : i); }

// ---- weight prep ----
// w1t[ch][kc8], kc8 = tap*8+c (pad 56..63 = 0).  w2t[ch][kc], kc = tap*96+c.
// bias2e[n] = b2[n] + sum_{tap,c} W2[tap][c][n] * b1[c]   (bias1 fold, exact)
__global__ void prep_kernel(const float* __restrict__ W1, const float* __restrict__ b1,
                            const float* __restrict__ W2, const float* __restrict__ b2,
                            unsigned short* __restrict__ w1t, unsigned short* __restrict__ w2t,
                            float* __restrict__ bias2e) {
  int i = blockIdx.x * 256 + threadIdx.x;
  if (i < 96 * 64) {
    int n = i >> 6, kc = i & 63;
    float v = (kc < 56) ? W1[kc * 96 + n] : 0.f;   // W1 flat [(tap*8+c)*96 + n]
    w1t[i] = f2bf(v);
  }
  if (i < 96 * 672) {
    int n = i / 672, kc = i - n * 672;
    w2t[i] = f2bf(W2[kc * 96 + n]);                // W2 flat [(tap*96+c)*96 + n]
  }
  if (blockIdx.x == 0 && threadIdx.x < 96) {
    int n = threadIdx.x;
    float s = b2[n];
#pragma unroll 8
    for (int kc = 0; kc < 672; ++kc) {
      int c = kc - (kc / 96) * 96;
      s += W2[kc * 96 + n] * b1[c];
    }
    bias2e[n] = s;
  }
}

// ==== kernel A: conv1 -> out1 (NHWC bf16). No LDS, no syncs. ====
__global__ __launch_bounds__(NTHREADS, 6)
void conv1_kernel(const float* __restrict__ x, const unsigned short* __restrict__ w1t,
                  unsigned short* __restrict__ o1g) {
  const int tid  = threadIdx.x;
  const int w0   = blockIdx.x * TW;
  const int h0   = blockIdx.y * TH1;
  const int b    = blockIdx.z;
  const int wid  = tid >> 6;        // channel tile
  const int lane = tid & 63;
  const int l15  = lane & 15;       // pixel
  const int g    = lane >> 4;
  const int cf   = wid * 16 + l15;  // A channel row

  bf16x8 w1a0 = ld16s(&w1t[cf * 64 + 8 * g]);        // taps 0..3
  bf16x8 w1a1 = ld16s(&w1t[cf * 64 + 32 + 8 * g]);   // taps 4..6 (+zero tap7)
  const i32x4 z4 = {0, 0, 0, 0};

  // per-lane source pixels (symmetric W pad); both in [0,255] for all lanes
  const int wc0 = symW(w0 - 3 + l15 + g);
  const int wc1 = symW(w0 - 3 + l15 + 4 + g);

  const float* xb = x + (size_t)b * H_ * W_ * CIN;
#pragma unroll
  for (int rr = 0; rr < TH1; ++rr) {
    const int h = h0 + rr;
    const float* p0 = xb + ((size_t)h * W_ + wc0) * CIN;
    float4 u0 = *(const float4*)p0, u1 = *(const float4*)(p0 + 4);
    unsigned a0 = ((unsigned)f2bf(u0.y) << 16) | f2bf(u0.x);
    unsigned a1 = ((unsigned)f2bf(u0.w) << 16) | f2bf(u0.z);
    unsigned a2 = ((unsigned)f2bf(u1.y) << 16) | f2bf(u1.x);
    unsigned a3 = ((unsigned)f2bf(u1.w) << 16) | f2bf(u1.z);
    bf16x8 xb0 = __builtin_bit_cast(bf16x8, (i32x4){(int)a0, (int)a1, (int)a2, (int)a3});
    bf16x8 xb1;
    if (g < 3) {
      const float* p1 = xb + ((size_t)h * W_ + wc1) * CIN;
      float4 v0 = *(const float4*)p1, v1 = *(const float4*)(p1 + 4);
      unsigned c0 = ((unsigned)f2bf(v0.y) << 16) | f2bf(v0.x);
      unsigned c1 = ((unsigned)f2bf(v0.w) << 16) | f2bf(v0.z);
      unsigned c2 = ((unsigned)f2bf(v1.y) << 16) | f2bf(v1.x);
      unsigned c3 = ((unsigned)f2bf(v1.w) << 16) | f2bf(v1.z);
      xb1 = __builtin_bit_cast(bf16x8, (i32x4){(int)c0, (int)c1, (int)c2, (int)c3});
    } else {
      xb1 = __builtin_bit_cast(bf16x8, z4);
    }
    f32x4 a = {0.f, 0.f, 0.f, 0.f};
    a = mfma16(w1a0, xb0, a);
    a = mfma16(w1a1, xb1, a);
    // D[m=ch 4g+r][n=pix l15] -> out1[b][h][w0+l15][16wid+4g .. +3], b64 store
    unsigned lo = ((unsigned)f2bf(a[1]) << 16) | f2bf(a[0]);
    unsigned hi = ((unsigned)f2bf(a[3]) << 16) | f2bf(a[2]);
    *(uint2*)&o1g[(((size_t)b * H_ + h) * W_ + w0 + l15) * COUT + wid * 16 + 4 * g] =
        make_uint2(lo, hi);
  }
}

// ==== kernel B: conv2 from out1 (global, L3-resident). No LDS, no syncs. ====
__global__ __launch_bounds__(NTHREADS, 4)   // VGPR cap 128; live ~115
void conv2_kernel(const unsigned short* __restrict__ o1g,
                  const unsigned short* __restrict__ w2t,
                  const float* __restrict__ bias2e, float* __restrict__ out) {
  const int tid  = threadIdx.x;
  const int w0   = blockIdx.x * TW;
  const int h0   = blockIdx.y * TH2;
  const int b    = blockIdx.z;
  const int wid  = tid >> 6;        // channel tile
  const int lane = tid & 63;
  const int l15  = lane & 15;       // pixel
  const int g    = lane >> 4;
  const int cf   = wid * 16 + l15;  // A channel row

  f32x4 acc[TH2];
#pragma unroll
  for (int m = 0; m < TH2; ++m) acc[m] = (f32x4){0.f, 0.f, 0.f, 0.f};

#pragma unroll 1                      // phase-local weight set (28 VGPR)
  for (int j = 0; j < 3; ++j) {
    bf16x8 w2f[7];
#pragma unroll
    for (int k = 0; k < 7; ++k)       // A[m=cf][kk=8g+jj] = W2[cf][tap k, c=32j+8g+jj]
      w2f[k] = ld16s(&w2t[cf * 672 + k * 96 + 32 * j + 8 * g]);
#pragma unroll
    for (int rr = 0; rr < RB; ++rr) {
      const int hr = symH(h0 - 3 + rr);   // block-uniform
      bf16x8 p = ld16s(&o1g[(((size_t)b * H_ + hr) * W_ + w0 + l15) * COUT + 32 * j + 8 * g]);
#pragma unroll
      for (int k = 0; k < 7; ++k) {
        int m = rr - k;               // output row; folds to constants
        if (m < 0 || m >= TH2) continue;
        acc[m] = mfma16(w2f[k], p, acc[m]);
      }
    }
  }

  const float4 bia = *(const float4*)&bias2e[wid * 16 + 4 * g];
  const size_t obase = (((size_t)b * H_ + h0) * W_ + (w0 + l15)) * COUT + wid * 16 + 4 * g;
#pragma unroll
  for (int m = 0; m < TH2; ++m) {
    f32x4 v = acc[m];
    v[0] += bia.x; v[1] += bia.y; v[2] += bia.z; v[3] += bia.w;
    __builtin_nontemporal_store(v, (f32x4*)(out + obase + (size_t)m * (W_ * COUT)));
  }
}

// ==== fallback: proven fused kernel (R6, 190.7us) if ws too small ====
__global__ __launch_bounds__(NTHREADS, 5)
void conv_fused(const float* __restrict__ x, const unsigned short* __restrict__ w1t,
                const unsigned short* __restrict__ w2t, const float* __restrict__ bias2e,
                float* __restrict__ out) {
  __shared__ __align__(16) unsigned short o1[ROWS][12][TW][8];
  __shared__ __align__(16) unsigned short xt[ROWS][XC][CIN];
  const int tid = threadIdx.x;
  const int w0  = blockIdx.x * TW;
  const int h0  = blockIdx.y * TH;
  const int b   = blockIdx.z;
  const int wid  = tid >> 6;
  const int lane = tid & 63;
  const int l15  = lane & 15;
  const int g    = lane >> 4;
  const int cf   = wid * 16 + l15;

  const float* xb = x + (size_t)b * H_ * W_ * CIN;
  if (tid < ROWS * XC) {
    int rr = tid / XC, cc = tid - rr * XC;
    int hr = symH(h0 - 3 + rr);
    int wc = symW(w0 - 3 + cc);
    const float4* px = (const float4*)(xb + ((size_t)hr * W_ + wc) * CIN);
    float4 v0 = px[0], v1 = px[1];
    unsigned p0 = ((unsigned)f2bf(v0.y) << 16) | f2bf(v0.x);
    unsigned p1 = ((unsigned)f2bf(v0.w) << 16) | f2bf(v0.z);
    unsigned p2 = ((unsigned)f2bf(v1.y) << 16) | f2bf(v1.x);
    unsigned p3 = ((unsigned)f2bf(v1.w) << 16) | f2bf(v1.z);
    *(i32x4*)&xt[rr][cc][0] = (i32x4){(int)p0, (int)p1, (int)p2, (int)p3};
  }
  bf16x8 w1a0 = ld16s(&w1t[cf * 64 + 8 * g]);
  bf16x8 w1a1 = ld16s(&w1t[cf * 64 + 32 + 8 * g]);
  const i32x4 z4 = {0, 0, 0, 0};
  __syncthreads();
#pragma unroll
  for (int rr = 0; rr < ROWS; ++rr) {
    bf16x8 xb0 = ld16s(&xt[rr][l15 + g][0]);
    bf16x8 xb1 = (g < 3) ? ld16s(&xt[rr][l15 + 4 + g][0]) : __builtin_bit_cast(bf16x8, z4);
    f32x4 a = {0.f, 0.f, 0.f, 0.f};
    a = mfma16(w1a0, xb0, a);
    a = mfma16(w1a1, xb1, a);
    unsigned lo = ((unsigned)f2bf(a[1]) << 16) | f2bf(a[0]);
    unsigned hi = ((unsigned)f2bf(a[3]) << 16) | f2bf(a[2]);
    *(uint2*)&o1[rr][2 * wid + (g >> 1)][l15][(g & 1) * 4] = make_uint2(lo, hi);
  }
  __syncthreads();
  f32x4 acc[TH];
#pragma unroll
  for (int m = 0; m < TH; ++m) acc[m] = (f32x4){0.f, 0.f, 0.f, 0.f};
#pragma unroll 1
  for (int j = 0; j < 3; ++j) {
    bf16x8 w2f[7];
#pragma unroll
    for (int k = 0; k < 7; ++k)
      w2f[k] = ld16s(&w2t[cf * 672 + k * 96 + 32 * j + 8 * g]);
#pragma unroll
    for (int rr = 0; rr < ROWS; ++rr) {
      bf16x8 p = ld16s(&o1[rr][4 * j + g][l15][0]);
#pragma unroll
      for (int k = 0; k < 7; ++k) {
        int m = rr - k;
        if (m < 0 || m >= TH) continue;
        acc[m] = mfma16(w2f[k], p, acc[m]);
      }
    }
  }
  const float4 bia = *(const float4*)&bias2e[wid * 16 + 4 * g];
  const size_t obase = (((size_t)b * H_ + h0) * W_ + (w0 + l15)) * COUT + wid * 16 + 4 * g;
#pragma unroll
  for (int m = 0; m < TH; ++m) {
    f32x4 v = acc[m];
    v[0] += bia.x; v[1] += bia.y; v[2] += bia.z; v[3] += bia.w;
    __builtin_nontemporal_store(v, (f32x4*)(out + obase + (size_t)m * (W_ * COUT)));
  }
}

extern "C" void kernel_launch(void* const* d_in, const int* in_sizes, int n_in,
                              void* d_out, int out_size, void* d_ws, size_t ws_size,
                              hipStream_t stream) {
  const float* x  = (const float*)d_in[0];
  const float* W1 = (const float*)d_in[1];
  const float* b1 = (const float*)d_in[2];
  const float* W2 = (const float*)d_in[3];
  const float* b2 = (const float*)d_in[4];
  // d_in[5] = training (unused)

  unsigned short* w1t = (unsigned short*)d_ws;       // 96*64 u16
  unsigned short* w2t = w1t + 96 * 64;               // 96*672 u16
  float* bias2e = (float*)(w2t + 96 * 672);          // 96 f32 -> ends at 141,696
  float* out = (float*)d_out;

  const size_t o1_off   = 141824;                    // 256B-aligned
  const size_t o1_bytes = (size_t)B_ * H_ * W_ * COUT * 2;  // 201,326,592

  prep_kernel<<<dim3(252), dim3(256), 0, stream>>>(W1, b1, W2, b2, w1t, w2t, bias2e);

  if (ws_size >= o1_off + o1_bytes) {
    unsigned short* o1g = (unsigned short*)((char*)d_ws + o1_off);
    conv1_kernel<<<dim3(W_ / TW, H_ / TH1, B_), dim3(NTHREADS), 0, stream>>>(x, w1t, o1g);
    conv2_kernel<<<dim3(W_ / TW, H_ / TH2, B_), dim3(NTHREADS), 0, stream>>>(
        o1g, w2t, bias2e, out);
  } else {
    conv_fused<<<dim3(W_ / TW, H_ / TH, B_), dim3(NTHREADS), 0, stream>>>(
        x, w1t, w2t, bias2e, out);
  }
}

// Round 10
// 187.791 us; speedup vs baseline: 2.3077x; 2.3077x over previous
//
#include <hip/hip_runtime.h>

// Fused Stream_PreNet: conv1 (1x7, 8->96) + conv2 (7x1, 96->96), symmetric pad,
// bf16 MFMA (16x16x32), swapped operands -> D[channel][pixel].
// R10 = R6 structure with TH=16 (halo/sync amortization):
//  - conv1 halo overhead 1.375x (was 1.75x); conv2 ds_reads/output -22%.
//  - o1 slot-major [22][12][16][8]: conflict-free b128, no pad, 67.6KB.
//  - conv2 in 3 c-slice passes (7 weight frags, 28 VGPR, unroll-1 pass loop).
//  - acc[16] (64 f32 -> AGPR file); launch_bounds(384,4) = 128 VGPR headroom.
//  - NO asm pin, NO M-split (R2/R4/R5/R7/R8 regressions); bias1 folded; NT stores.
// d_ws: w1t (96*64 bf16) + w2t (96*672 bf16) + bias2e (96 f32) = 141,696 B.

#define B_   8
#define H_   512
#define W_   256
#define CIN  8
#define COUT 96
#define TH   16           // output rows per block
#define TW   16           // output cols per block
#define ROWS (TH + 6)     // 22 out1 rows (halo for 7x1)
#define XC   (TW + 6)     // 22 x cols (halo for 1x7)
#define NTHREADS 384      // 6 waves; wave w owns channels [16w, 16w+16)

typedef __bf16 bf16x8 __attribute__((ext_vector_type(8)));
typedef float  f32x4  __attribute__((ext_vector_type(4)));
typedef int    i32x4  __attribute__((ext_vector_type(4)));

__device__ __forceinline__ unsigned short f2bf(float f) {
  unsigned u = __builtin_bit_cast(unsigned, f);
  u += 0x7FFFu + ((u >> 16) & 1u);   // RNE
  return (unsigned short)(u >> 16);
}

__device__ __forceinline__ bf16x8 ld16s(const unsigned short* p) {
  i32x4 t = *(const i32x4*)p;        // 16B load -> ds_read_b128 / dwordx4
  return __builtin_bit_cast(bf16x8, t);
}

__device__ __forceinline__ f32x4 mfma16(bf16x8 a, bf16x8 b, f32x4 c) {
  return __builtin_amdgcn_mfma_f32_16x16x32_bf16(a, b, c, 0, 0, 0);
}

// jnp.pad mode='symmetric': -1->0, -2->1 ; N->N-1, N+1->N-2
__device__ __forceinline__ int symH(int i) { return i < 0 ? -1 - i : (i >= H_ ? 2 * H_ - 1 - i : i); }
__device__ __forceinline__ int symW(int i) { return i < 0 ? -1 - i : (i >= W_ ? 2 * W_ - 1 - i : i); }

// ---- weight prep ----
// w1t[ch][kc8], kc8 = tap*8+c (pad 56..63 = 0).  w2t[ch][kc], kc = tap*96+c.
// bias2e[n] = b2[n] + sum_{tap,c} W2[tap][c][n] * b1[c]   (bias1 fold, exact)
__global__ void prep_kernel(const float* __restrict__ W1, const float* __restrict__ b1,
                            const float* __restrict__ W2, const float* __restrict__ b2,
                            unsigned short* __restrict__ w1t, unsigned short* __restrict__ w2t,
                            float* __restrict__ bias2e) {
  int i = blockIdx.x * 256 + threadIdx.x;
  if (i < 96 * 64) {
    int n = i >> 6, kc = i & 63;
    float v = (kc < 56) ? W1[kc * 96 + n] : 0.f;   // W1 flat [(tap*8+c)*96 + n]
    w1t[i] = f2bf(v);
  }
  if (i < 96 * 672) {
    int n = i / 672, kc = i - n * 672;
    w2t[i] = f2bf(W2[kc * 96 + n]);                // W2 flat [(tap*96+c)*96 + n]
  }
  if (blockIdx.x == 0 && threadIdx.x < 96) {
    int n = threadIdx.x;
    float s = b2[n];
#pragma unroll 8
    for (int kc = 0; kc < 672; ++kc) {
      int c = kc - (kc / 96) * 96;
      s += W2[kc * 96 + n] * b1[c];
    }
    bias2e[n] = s;
  }
}

__global__ __launch_bounds__(NTHREADS, 4)   // VGPR cap 128 (acc[16] -> AGPRs)
void conv_main(const float* __restrict__ x, const unsigned short* __restrict__ w1t,
               const unsigned short* __restrict__ w2t, const float* __restrict__ bias2e,
               float* __restrict__ out) {
  // o1 slot-major: [row][slot=ch/8][pixel][8 ch] -> conflict-free b128, no pad.
  __shared__ __align__(16) unsigned short o1[ROWS][12][TW][8];  // 67,584 B
  __shared__ __align__(16) unsigned short xt[ROWS][XC][CIN];    //  7,744 B

  const int tid = threadIdx.x;
  const int w0  = blockIdx.x * TW;
  const int h0  = blockIdx.y * TH;
  const int b   = blockIdx.z;

  const int wid  = tid >> 6;        // wave id = channel tile
  const int lane = tid & 63;
  const int l15  = lane & 15;       // A: ch-in-tile / B,D: pixel
  const int g    = lane >> 4;       // k-group; D rows 4g..4g+3
  const int cf   = wid * 16 + l15;  // this wave's A channel row

  // ---- stage x halo tile (symmetric pad applied), fp32 -> bf16 ----
  const float* xb = x + (size_t)b * H_ * W_ * CIN;
  for (int idx = tid; idx < ROWS * XC; idx += NTHREADS) {
    int rr = idx / XC, cc = idx - rr * XC;
    int hr = symH(h0 - 3 + rr);
    int wc = symW(w0 - 3 + cc);
    const float4* px = (const float4*)(xb + ((size_t)hr * W_ + wc) * CIN);
    float4 v0 = px[0], v1 = px[1];
    unsigned p0 = ((unsigned)f2bf(v0.y) << 16) | f2bf(v0.x);
    unsigned p1 = ((unsigned)f2bf(v0.w) << 16) | f2bf(v0.z);
    unsigned p2 = ((unsigned)f2bf(v1.y) << 16) | f2bf(v1.x);
    unsigned p3 = ((unsigned)f2bf(v1.w) << 16) | f2bf(v1.z);
    *(i32x4*)&xt[rr][cc][0] = (i32x4){(int)p0, (int)p1, (int)p2, (int)p3};
  }

  // conv1 A-frags (weights): A[m=ch][k=tap*8+c]  (8 VGPR)
  bf16x8 w1a0 = ld16s(&w1t[cf * 64 + 8 * g]);        // taps 0..3
  bf16x8 w1a1 = ld16s(&w1t[cf * 64 + 32 + 8 * g]);   // taps 4..6 (+zero tap7)
  const i32x4 z4 = {0, 0, 0, 0};

  __syncthreads();

  // ---- conv1: each wave does all 22 rows for its 16 channels ----
#pragma unroll
  for (int rr = 0; rr < ROWS; ++rr) {
    // B[k=tap*8+c][n=pixel] = xt[rr][pixel + tap][c]
    // g==3 -> tap 7: weight rows zero, but xt[rr][l15+7] can be OOB -> zero load.
    bf16x8 xb0 = ld16s(&xt[rr][l15 + g][0]);
    bf16x8 xb1 = (g < 3) ? ld16s(&xt[rr][l15 + 4 + g][0]) : __builtin_bit_cast(bf16x8, z4);
    f32x4 a = {0.f, 0.f, 0.f, 0.f};
    a = mfma16(w1a0, xb0, a);
    a = mfma16(w1a1, xb1, a);
    // ch = 16wid+4g+r -> slot 2wid+(g>>1), intra-slot (g&1)*4+r ; packed b64 write
    unsigned lo = ((unsigned)f2bf(a[1]) << 16) | f2bf(a[0]);
    unsigned hi = ((unsigned)f2bf(a[3]) << 16) | f2bf(a[2]);
    *(uint2*)&o1[rr][2 * wid + (g >> 1)][l15][(g & 1) * 4] = make_uint2(lo, hi);
  }

  __syncthreads();

  // ---- conv2 in 3 c-slice passes: pass j covers channels-in 32j..32j+31 ----
  f32x4 acc[TH];
#pragma unroll
  for (int m = 0; m < TH; ++m) acc[m] = (f32x4){0.f, 0.f, 0.f, 0.f};

#pragma unroll 1                      // do NOT hoist all 21 weight frags
  for (int j = 0; j < 3; ++j) {
    bf16x8 w2f[7];
#pragma unroll
    for (int k = 0; k < 7; ++k)       // A[m=cf][kk=8g+jj] = W2[cf][tap k, c=32j+8g+jj]
      w2f[k] = ld16s(&w2t[cf * 672 + k * 96 + 32 * j + 8 * g]);
#pragma unroll
    for (int rr = 0; rr < ROWS; ++rr) {
      bf16x8 p = ld16s(&o1[rr][4 * j + g][l15][0]);   // B[k=c][n=pix]
#pragma unroll
      for (int k = 0; k < 7; ++k) {
        int m = rr - k;               // output row; folds to constants
        if (m < 0 || m >= TH) continue;
        acc[m] = mfma16(w2f[k], p, acc[m]);
      }
    }
  }

  // ---- epilogue: lane holds 4 consecutive channels at pixel l15 -> NT float4 ----
  const float4 bia = *(const float4*)&bias2e[wid * 16 + 4 * g];
  const size_t obase = (((size_t)b * H_ + h0) * W_ + (w0 + l15)) * COUT + wid * 16 + 4 * g;
#pragma unroll
  for (int m = 0; m < TH; ++m) {
    f32x4 v = acc[m];
    v[0] += bia.x; v[1] += bia.y; v[2] += bia.z; v[3] += bia.w;
    __builtin_nontemporal_store(v, (f32x4*)(out + obase + (size_t)m * (W_ * COUT)));
  }
}

extern "C" void kernel_launch(void* const* d_in, const int* in_sizes, int n_in,
                              void* d_out, int out_size, void* d_ws, size_t ws_size,
                              hipStream_t stream) {
  const float* x  = (const float*)d_in[0];
  const float* W1 = (const float*)d_in[1];
  const float* b1 = (const float*)d_in[2];
  const float* W2 = (const float*)d_in[3];
  const float* b2 = (const float*)d_in[4];
  // d_in[5] = training (unused)

  unsigned short* w1t = (unsigned short*)d_ws;       // 96*64 u16
  unsigned short* w2t = w1t + 96 * 64;               // 96*672 u16
  float* bias2e = (float*)(w2t + 96 * 672);          // 96 f32
  float* out = (float*)d_out;

  prep_kernel<<<dim3(252), dim3(256), 0, stream>>>(W1, b1, W2, b2, w1t, w2t, bias2e);
  conv_main<<<dim3(W_ / TW, H_ / TH, B_), dim3(NTHREADS), 0, stream>>>(
      x, w1t, w2t, bias2e, out);
}

// Round 11
// 145.736 us; speedup vs baseline: 2.9736x; 1.2886x over previous
//
#include <hip/hip_runtime.h>

// Stream_PreNet as ONE composed 7x7 conv (exact algebra):
//   conv2(7x1) ∘ conv1(1x7) with per-axis symmetric pad ==
//   out[h][w][n] = sum_{th,tw,c} Wc[th][tw][c][n] * x[symH(h+th-3)][symW(w+tw-3)][c] + bias2e[n]
//   Wc[th][tw][c][n] = sum_m W2[th][m][n] * W1[tw][c][m]   (composed in fp32 on device)
//   bias2e[n] = b2[n] + sum_{th,m} W2[th][m][n]*b1[m]      (same fold as before)
// K = 7*7*8 = 392 -> padded 416 = 13 MFMA k-slices. Single-phase kernel:
// stage x tile -> barrier -> 13x8 {ds_read_b128 + mfma} -> NT stores.
// No o1 intermediate (no writes, no repack, no 2nd barrier, no extra rounding).
// B-frag pattern identical to proven conv1: k = 8*pair + c, c contiguous 16B.
// d_ws: wct (96*416 bf16 = 79,872 B) + bias2e (96 f32) = 80,256 B.

#define B_   8
#define H_   512
#define W_   256
#define CIN  8
#define COUT 96
#define TH   8            // output rows per block
#define TW   16           // output cols per block
#define RS   (TH + 6)     // 14 staged x rows
#define XC   22           // staged x cols used (TW+6)
#define XCP  23           // padded col stride (bank rotation)
#define KP   416          // padded K (13 slices of 32)
#define NTHREADS 384      // 6 waves; wave w owns channels [16w, 16w+16)

typedef __bf16 bf16x8 __attribute__((ext_vector_type(8)));
typedef float  f32x4  __attribute__((ext_vector_type(4)));
typedef int    i32x4  __attribute__((ext_vector_type(4)));

__device__ __forceinline__ unsigned short f2bf(float f) {
  unsigned u = __builtin_bit_cast(unsigned, f);
  u += 0x7FFFu + ((u >> 16) & 1u);   // RNE
  return (unsigned short)(u >> 16);
}

__device__ __forceinline__ bf16x8 ld16s(const unsigned short* p) {
  i32x4 t = *(const i32x4*)p;        // 16B load -> ds_read_b128 / dwordx4
  return __builtin_bit_cast(bf16x8, t);
}

__device__ __forceinline__ f32x4 mfma16(bf16x8 a, bf16x8 b, f32x4 c) {
  return __builtin_amdgcn_mfma_f32_16x16x32_bf16(a, b, c, 0, 0, 0);
}

// jnp.pad mode='symmetric': -1->0, -2->1 ; N->N-1, N+1->N-2
__device__ __forceinline__ int symH(int i) { return i < 0 ? -1 - i : (i >= H_ ? 2 * H_ - 1 - i : i); }
__device__ __forceinline__ int symW(int i) { return i < 0 ? -1 - i : (i >= W_ ? 2 * W_ - 1 - i : i); }

// ---- prep: compose Wc in fp32, cast once to bf16; fold bias1 ----
// wct[n][k], k = p*8 + c, p = th*7+tw (p>=49 zero-padded).
__global__ void prep_kernel(const float* __restrict__ W1, const float* __restrict__ b1,
                            const float* __restrict__ W2, const float* __restrict__ b2,
                            unsigned short* __restrict__ wct, float* __restrict__ bias2e) {
  int i = blockIdx.x * 256 + threadIdx.x;      // 156 blocks x 256 = 96*416 exactly
  if (i < 96 * KP) {
    int n = i / KP, k = i - n * KP;
    int p = k >> 3, c = k & 7;
    float s = 0.f;
    if (p < 49) {
      int th = p / 7, tw = p - 7 * th;
#pragma unroll 8
      for (int m = 0; m < 96; ++m)             // W2[(th*96+m)*96+n] * W1[(tw*8+c)*96+m]
        s += W2[(th * 96 + m) * 96 + n] * W1[(tw * 8 + c) * 96 + m];
    }
    wct[i] = f2bf(s);
  }
  if (i < 96) {
    float s = b2[i];
#pragma unroll 8
    for (int kc = 0; kc < 672; ++kc) {
      int m = kc - (kc / 96) * 96;
      s += W2[kc * 96 + i] * b1[m];
    }
    bias2e[i] = s;
  }
}

__global__ __launch_bounds__(NTHREADS, 5)      // VGPR cap ~102 -> 3 blocks/CU
void conv7(const float* __restrict__ x, const unsigned short* __restrict__ wct,
           const float* __restrict__ bias2e, float* __restrict__ out) {
  __shared__ __align__(16) unsigned short xt[RS][XCP][CIN];   // 5,152 B

  const int tid = threadIdx.x;
  const int w0  = blockIdx.x * TW;
  const int h0  = blockIdx.y * TH;
  const int b   = blockIdx.z;

  const int wid  = tid >> 6;        // wave id = channel tile
  const int lane = tid & 63;
  const int l15  = lane & 15;       // A: ch-in-tile / B,D: pixel
  const int g    = lane >> 4;       // k-group
  const int cf   = wid * 16 + l15;  // output channel (A row)

  // ---- stage x halo tile (symmetric pad applied), fp32 -> bf16 ----
  const float* xb = x + (size_t)b * H_ * W_ * CIN;
  if (tid < RS * XC) {
    int rr = tid / XC, cc = tid - rr * XC;
    int hr = symH(h0 - 3 + rr);
    int wc = symW(w0 - 3 + cc);
    const float4* px = (const float4*)(xb + ((size_t)hr * W_ + wc) * CIN);
    float4 v0 = px[0], v1 = px[1];
    unsigned p0 = ((unsigned)f2bf(v0.y) << 16) | f2bf(v0.x);
    unsigned p1 = ((unsigned)f2bf(v0.w) << 16) | f2bf(v0.z);
    unsigned p2 = ((unsigned)f2bf(v1.y) << 16) | f2bf(v1.x);
    unsigned p3 = ((unsigned)f2bf(v1.w) << 16) | f2bf(v1.z);
    *(i32x4*)&xt[rr][cc][0] = (i32x4){(int)p0, (int)p1, (int)p2, (int)p3};
  }

  const unsigned short* wrow = wct + (size_t)cf * KP;
  const i32x4 z4 = {0, 0, 0, 0};

  f32x4 acc[TH];
#pragma unroll
  for (int m = 0; m < TH; ++m) acc[m] = (f32x4){0.f, 0.f, 0.f, 0.f};

  __syncthreads();

  // ---- 13 K-slices in two phase-local passes (7 + 6 weight frags) ----
#pragma unroll 1
  for (int pass = 0; pass < 2; ++pass) {
    if (pass == 0) {
      bf16x8 wf[7];
#pragma unroll
      for (int s = 0; s < 7; ++s) wf[s] = ld16s(&wrow[32 * s + 8 * g]);
#pragma unroll
      for (int s = 0; s < 7; ++s) {
        int p = 4 * s + g;                  // pair index; th<=3 here
        int th = p / 7, tw = p - 7 * th;
        const unsigned short* bp = &xt[th][l15 + tw][0];
#pragma unroll
        for (int m = 0; m < TH; ++m)        // B[k=8p+c][n=pix] = xt[m+th][l15+tw][c]
          acc[m] = mfma16(wf[s], ld16s(bp + m * XCP * CIN), acc[m]);
      }
    } else {
      bf16x8 wf[6];
#pragma unroll
      for (int s = 0; s < 6; ++s) wf[s] = ld16s(&wrow[32 * (7 + s) + 8 * g]);
#pragma unroll
      for (int s = 0; s < 6; ++s) {
        int p = 4 * (7 + s) + g;
        int th = p / 7, tw = p - 7 * th;
        const unsigned short* bp = &xt[th][l15 + tw][0];
        if (s < 5) {
#pragma unroll
          for (int m = 0; m < TH; ++m)
            acc[m] = mfma16(wf[s], ld16s(bp + m * XCP * CIN), acc[m]);
        } else {
          // slice 12: pairs 49..51 (g>0) are zero-weight and their row index
          // (m+7) runs past xt -> select zero B (read is exec-masked/discarded).
#pragma unroll
          for (int m = 0; m < TH; ++m) {
            bf16x8 xv = (g == 0) ? ld16s(bp + m * XCP * CIN)
                                 : __builtin_bit_cast(bf16x8, z4);
            acc[m] = mfma16(wf[s], xv, acc[m]);
          }
        }
      }
    }
  }

  // ---- epilogue: lane holds 4 consecutive channels at pixel l15 -> NT float4 ----
  const float4 bia = *(const float4*)&bias2e[wid * 16 + 4 * g];
  const size_t obase = (((size_t)b * H_ + h0) * W_ + (w0 + l15)) * COUT + wid * 16 + 4 * g;
#pragma unroll
  for (int m = 0; m < TH; ++m) {
    f32x4 v = acc[m];
    v[0] += bia.x; v[1] += bia.y; v[2] += bia.z; v[3] += bia.w;
    __builtin_nontemporal_store(v, (f32x4*)(out + obase + (size_t)m * (W_ * COUT)));
  }
}

extern "C" void kernel_launch(void* const* d_in, const int* in_sizes, int n_in,
                              void* d_out, int out_size, void* d_ws, size_t ws_size,
                              hipStream_t stream) {
  const float* x  = (const float*)d_in[0];
  const float* W1 = (const float*)d_in[1];
  const float* b1 = (const float*)d_in[2];
  const float* W2 = (const float*)d_in[3];
  const float* b2 = (const float*)d_in[4];
  // d_in[5] = training (unused)

  unsigned short* wct = (unsigned short*)d_ws;       // 96*416 u16
  float* bias2e = (float*)(wct + 96 * KP);           // 96 f32
  float* out = (float*)d_out;

  prep_kernel<<<dim3(156), dim3(256), 0, stream>>>(W1, b1, W2, b2, wct, bias2e);
  conv7<<<dim3(W_ / TW, H_ / TH, B_), dim3(NTHREADS), 0, stream>>>(
      x, wct, bias2e, out);
}